// Round 1
// baseline (189.816 us; speedup 1.0000x reference)
//
#include <hip/hip_runtime.h>
#include <hip/hip_bf16.h>
#include <stdint.h>

typedef __bf16 bf16;
typedef __bf16 bf16x8 __attribute__((ext_vector_type(8)));
typedef __bf16 bf16x4 __attribute__((ext_vector_type(4)));
typedef float  f32x4  __attribute__((ext_vector_type(4)));

#define DM 1024
#define NH 16
#define HD 64
#define TT 2048

// fp32 -> bf16 convert, float4 vectorized
__global__ void cvt_f32_bf16(const float* __restrict__ in, bf16* __restrict__ out, int n) {
  int i = (blockIdx.x * blockDim.x + threadIdx.x) * 4;
  if (i < n) {
    const float4 v = *reinterpret_cast<const float4*>(in + i);
    bf16x4 o = { (bf16)v.x, (bf16)v.y, (bf16)v.z, (bf16)v.w };
    *reinterpret_cast<bf16x4*>(out + i) = o;
  }
}

static __device__ __forceinline__ void gload_lds16(const bf16* g, bf16* l) {
  __builtin_amdgcn_global_load_lds(
      (__attribute__((address_space(1))) void*)g,
      (__attribute__((address_space(3))) void*)l, 16, 0, 0);
}

// C = X @ W^T for 3 weight matrices; scatter epilogue into attention layouts.
// X: [4096,1024] bf16 row-major. W*: [1024,1024] bf16 row-major (n,k).
// Qb/Kb: [32 bh][2048 t][64 d]; Vtb: [32 bh][64 d][2048 t]. Q pre-scaled 1/8.
__launch_bounds__(256, 2)
__global__ void gemm_qkv(const bf16* __restrict__ X, const bf16* __restrict__ Wq,
                         const bf16* __restrict__ Wk, const bf16* __restrict__ Wv,
                         bf16* __restrict__ Qb, bf16* __restrict__ Kb,
                         bf16* __restrict__ Vtb) {
  __shared__ bf16 As[128 * 32];
  __shared__ bf16 Bs[128 * 32];
  const int tid  = threadIdx.x;
  const int lane = tid & 63;
  const int wv   = tid >> 6;
  const int lg   = lane >> 4, lc = lane & 15;
  const int m0   = blockIdx.x * 128;
  const int ng   = blockIdx.y * 128;
  const int which = ng >> 10;                 // 0=Q 1=K 2=V
  const bf16* W = (which == 0) ? Wq : ((which == 1) ? Wk : Wv);
  const int n0 = ng & 1023;
  const int wm = wv >> 1, wn = wv & 1;

  f32x4 acc[4][4] = {};

  for (int k0 = 0; k0 < DM; k0 += 32) {
#pragma unroll
    for (int c = 0; c < 2; ++c) {
      const int e   = wv * 512 + c * 2048 + lane * 8;
      const int row = e >> 5, col = e & 31;
      gload_lds16(X + (size_t)(m0 + row) * DM + k0 + col, &As[wv * 512 + c * 2048]);
      gload_lds16(W + (size_t)(n0 + row) * DM + k0 + col, &Bs[wv * 512 + c * 2048]);
    }
    __syncthreads();
    bf16x8 a[4], b[4];
#pragma unroll
    for (int i = 0; i < 4; ++i)
      a[i] = *reinterpret_cast<const bf16x8*>(&As[(wm * 64 + i * 16 + lc) * 32 + lg * 8]);
#pragma unroll
    for (int j = 0; j < 4; ++j)
      b[j] = *reinterpret_cast<const bf16x8*>(&Bs[(wn * 64 + j * 16 + lc) * 32 + lg * 8]);
#pragma unroll
    for (int i = 0; i < 4; ++i)
#pragma unroll
      for (int j = 0; j < 4; ++j)
        acc[i][j] = __builtin_amdgcn_mfma_f32_16x16x32_bf16(a[i], b[j], acc[i][j], 0, 0, 0);
    __syncthreads();
  }

  // epilogue: C row = (lane>>4)*4+reg (m/token), col = lane&15 (n)
#pragma unroll
  for (int i = 0; i < 4; ++i) {
    const int mg = m0 + wm * 64 + i * 16 + lg * 4;
    const int bb = mg >> 11, t = mg & 2047;
#pragma unroll
    for (int j = 0; j < 4; ++j) {
      const int nl = n0 + wn * 64 + j * 16 + lc;
      const int h = nl >> 6, d = nl & 63;
      const int bh = bb * NH + h;
      const f32x4 v = acc[i][j];
      if (which == 0) {
        bf16* p = Qb + ((size_t)bh * TT + t) * HD + d;
#pragma unroll
        for (int r = 0; r < 4; ++r) p[r * HD] = (bf16)(v[r] * 0.125f);
      } else if (which == 1) {
        bf16* p = Kb + ((size_t)bh * TT + t) * HD + d;
#pragma unroll
        for (int r = 0; r < 4; ++r) p[r * HD] = (bf16)v[r];
      } else {
        bf16x4 pk = { (bf16)v[0], (bf16)v[1], (bf16)v[2], (bf16)v[3] };
        *reinterpret_cast<bf16x4*>(Vtb + ((size_t)bh * HD + d) * TT + t) = pk;
      }
    }
  }
}

#define KVB 64
#define KPAD 72   // 64 + 8 pad: stride 144B -> 2-way bank aliasing only (free)

__launch_bounds__(256, 2)
__global__ void attn_fwd(const bf16* __restrict__ Qb, const bf16* __restrict__ Kb,
                         const bf16* __restrict__ Vtb, bf16* __restrict__ Yb) {
  __shared__ bf16 Ks[KVB * KPAD];       // [t][d]
  __shared__ bf16 Vs[HD * KPAD];        // [d][t]
  __shared__ bf16 Ps[4 * 16 * KPAD];    // per-wave P [16 q][64 kv]

  const int tid  = threadIdx.x;
  const int lane = tid & 63;
  const int wv   = tid >> 6;
  const int lg   = lane >> 4;
  const int lc   = lane & 15;
  const int bh   = blockIdx.x >> 5;
  const int qblk = blockIdx.x & 31;
  const int q0   = qblk * 64;
  const int qw   = q0 + wv * 16;        // this wave's first q row

  const bf16* Qg = Qb  + (size_t)bh * TT * HD;
  const bf16* Kg = Kb  + (size_t)bh * TT * HD;
  const bf16* Vg = Vtb + (size_t)bh * HD * TT;

  // Q fragments held in registers for the whole block (already scaled 1/8)
  bf16x8 qf[2];
#pragma unroll
  for (int ks = 0; ks < 2; ++ks)
    qf[ks] = *reinterpret_cast<const bf16x8*>(Qg + (size_t)(qw + lc) * HD + ks * 32 + lg * 8);

  f32x4 o[4] = {};
  float m_run[4], l_run[4];
#pragma unroll
  for (int r = 0; r < 4; ++r) { m_run[r] = -INFINITY; l_run[r] = 0.f; }

  const int ntiles = qblk + 1;
  for (int ti = 0; ti < ntiles; ++ti) {
    const int k0 = ti * KVB;
    // cooperative stage: K tile [64 t][64 d], V^T tile [64 d][64 t]
#pragma unroll
    for (int c = 0; c < 2; ++c) {
      const int e  = c * 2048 + tid * 8;
      const int rr = e >> 6, cc = e & 63;
      *reinterpret_cast<bf16x8*>(&Ks[rr * KPAD + cc]) =
          *reinterpret_cast<const bf16x8*>(Kg + (size_t)(k0 + rr) * HD + cc);
      *reinterpret_cast<bf16x8*>(&Vs[rr * KPAD + cc]) =
          *reinterpret_cast<const bf16x8*>(Vg + (size_t)rr * TT + k0 + cc);
    }
    __syncthreads();

    // S = Q K^T : 4 col-fragments of 16, K-dim 64 = 2 MFMAs each
    f32x4 s[4];
#pragma unroll
    for (int j = 0; j < 4; ++j) {
      f32x4 z = {};
#pragma unroll
      for (int ks = 0; ks < 2; ++ks) {
        const bf16x8 kf = *reinterpret_cast<const bf16x8*>(
            &Ks[(j * 16 + lc) * KPAD + ks * 32 + lg * 8]);
        z = __builtin_amdgcn_mfma_f32_16x16x32_bf16(qf[ks], kf, z, 0, 0, 0);
      }
      s[j] = z;
    }

    // causal mask only on the diagonal tile
    if (k0 == q0) {
#pragma unroll
      for (int j = 0; j < 4; ++j)
#pragma unroll
        for (int r = 0; r < 4; ++r)
          if (k0 + j * 16 + lc > qw + lg * 4 + r) s[j][r] = -INFINITY;
    }

    // online softmax: row = q (lane holds 4 rows via regs), cols across 16 lanes
    float rmax[4], rsum[4];
#pragma unroll
    for (int r = 0; r < 4; ++r)
      rmax[r] = fmaxf(fmaxf(s[0][r], s[1][r]), fmaxf(s[2][r], s[3][r]));
#pragma unroll
    for (int msk = 1; msk < 16; msk <<= 1)
#pragma unroll
      for (int r = 0; r < 4; ++r)
        rmax[r] = fmaxf(rmax[r], __shfl_xor(rmax[r], msk));

    float alpha[4];
#pragma unroll
    for (int r = 0; r < 4; ++r) {
      const float mn = fmaxf(m_run[r], rmax[r]);
      alpha[r] = __expf(m_run[r] - mn);
      m_run[r] = mn;
      rsum[r]  = 0.f;
    }
#pragma unroll
    for (int j = 0; j < 4; ++j)
#pragma unroll
      for (int r = 0; r < 4; ++r) {
        const float p = __expf(s[j][r] - m_run[r]);
        s[j][r] = p;
        rsum[r] += p;
      }
#pragma unroll
    for (int msk = 1; msk < 16; msk <<= 1)
#pragma unroll
      for (int r = 0; r < 4; ++r)
        rsum[r] += __shfl_xor(rsum[r], msk);
#pragma unroll
    for (int r = 0; r < 4; ++r) l_run[r] = l_run[r] * alpha[r] + rsum[r];
#pragma unroll
    for (int df = 0; df < 4; ++df)
#pragma unroll
      for (int r = 0; r < 4; ++r) o[df][r] *= alpha[r];

    // P -> LDS (re-fragment for PV A-operand)
    bf16* Pw = &Ps[wv * 16 * KPAD];
#pragma unroll
    for (int j = 0; j < 4; ++j)
#pragma unroll
      for (int r = 0; r < 4; ++r)
        Pw[(lg * 4 + r) * KPAD + j * 16 + lc] = (bf16)s[j][r];
    __syncthreads();

    // O += P V : 4 d-fragments, kv-dim 64 = 2 MFMAs each
#pragma unroll
    for (int ks = 0; ks < 2; ++ks) {
      const bf16x8 pf = *reinterpret_cast<const bf16x8*>(&Pw[lc * KPAD + ks * 32 + lg * 8]);
#pragma unroll
      for (int df = 0; df < 4; ++df) {
        const bf16x8 vf = *reinterpret_cast<const bf16x8*>(
            &Vs[(df * 16 + lc) * KPAD + ks * 32 + lg * 8]);
        o[df] = __builtin_amdgcn_mfma_f32_16x16x32_bf16(pf, vf, o[df], 0, 0, 0);
      }
    }
    __syncthreads();
  }

  // normalize + write y in [b*T + t][h*64 + d] bf16 layout
  const int b = bh >> 4, h = bh & 15;
  float inv[4];
#pragma unroll
  for (int r = 0; r < 4; ++r) inv[r] = 1.f / fmaxf(l_run[r], 1e-9f);
#pragma unroll
  for (int df = 0; df < 4; ++df)
#pragma unroll
    for (int r = 0; r < 4; ++r) {
      const int q = qw + lg * 4 + r;
      Yb[((size_t)(b * TT + q)) * DM + h * HD + df * 16 + lc] = (bf16)(o[df][r] * inv[r]);
    }
}

// Out = Y @ Wo^T, fp32 output row-major [4096,1024]
__launch_bounds__(256, 2)
__global__ void gemm_out(const bf16* __restrict__ Y, const bf16* __restrict__ Wo,
                         float* __restrict__ Out) {
  __shared__ bf16 As[128 * 32];
  __shared__ bf16 Bs[128 * 32];
  const int tid  = threadIdx.x;
  const int lane = tid & 63;
  const int wv   = tid >> 6;
  const int lg   = lane >> 4, lc = lane & 15;
  const int m0   = blockIdx.x * 128;
  const int n0   = blockIdx.y * 128;
  const int wm = wv >> 1, wn = wv & 1;

  f32x4 acc[4][4] = {};

  for (int k0 = 0; k0 < DM; k0 += 32) {
#pragma unroll
    for (int c = 0; c < 2; ++c) {
      const int e   = wv * 512 + c * 2048 + lane * 8;
      const int row = e >> 5, col = e & 31;
      gload_lds16(Y  + (size_t)(m0 + row) * DM + k0 + col, &As[wv * 512 + c * 2048]);
      gload_lds16(Wo + (size_t)(n0 + row) * DM + k0 + col, &Bs[wv * 512 + c * 2048]);
    }
    __syncthreads();
    bf16x8 a[4], b[4];
#pragma unroll
    for (int i = 0; i < 4; ++i)
      a[i] = *reinterpret_cast<const bf16x8*>(&As[(wm * 64 + i * 16 + lc) * 32 + lg * 8]);
#pragma unroll
    for (int j = 0; j < 4; ++j)
      b[j] = *reinterpret_cast<const bf16x8*>(&Bs[(wn * 64 + j * 16 + lc) * 32 + lg * 8]);
#pragma unroll
    for (int i = 0; i < 4; ++i)
#pragma unroll
      for (int j = 0; j < 4; ++j)
        acc[i][j] = __builtin_amdgcn_mfma_f32_16x16x32_bf16(a[i], b[j], acc[i][j], 0, 0, 0);
    __syncthreads();
  }

#pragma unroll
  for (int i = 0; i < 4; ++i) {
    const int mg = m0 + wm * 64 + i * 16 + lg * 4;
#pragma unroll
    for (int j = 0; j < 4; ++j) {
      const int n = n0 + wn * 64 + j * 16 + lc;
#pragma unroll
      for (int r = 0; r < 4; ++r)
        Out[(size_t)(mg + r) * DM + n] = acc[i][j][r];
    }
  }
}

extern "C" void kernel_launch(void* const* d_in, const int* in_sizes, int n_in,
                              void* d_out, int out_size, void* d_ws, size_t ws_size,
                              hipStream_t stream) {
  const float* x  = (const float*)d_in[0];
  const float* Wq = (const float*)d_in[1];
  const float* Wk = (const float*)d_in[2];
  const float* Wv = (const float*)d_in[3];
  const float* Wo = (const float*)d_in[4];
  float* out = (float*)d_out;
  char* ws = (char*)d_ws;
  const size_t MB = 1024 * 1024;

  bf16* xb  = (bf16*)(ws + 0);        // 8 MB, reused as yb after QKV GEMM
  bf16* wqb = (bf16*)(ws + 8  * MB);  // 2 MB
  bf16* wkb = (bf16*)(ws + 10 * MB);
  bf16* wvb = (bf16*)(ws + 12 * MB);
  bf16* wob = (bf16*)(ws + 14 * MB);
  bf16* Qb  = (bf16*)(ws + 16 * MB);  // 8 MB  [32,2048,64]
  bf16* Kb  = (bf16*)(ws + 24 * MB);  // 8 MB
  bf16* Vtb = (bf16*)(ws + 32 * MB);  // 8 MB  [32,64,2048]
  bf16* yb  = xb;                     // alias: x dead after gemm_qkv

  cvt_f32_bf16<<<4096, 256, 0, stream>>>(x,  xb,  4194304);
  cvt_f32_bf16<<<1024, 256, 0, stream>>>(Wq, wqb, 1048576);
  cvt_f32_bf16<<<1024, 256, 0, stream>>>(Wk, wkb, 1048576);
  cvt_f32_bf16<<<1024, 256, 0, stream>>>(Wv, wvb, 1048576);
  cvt_f32_bf16<<<1024, 256, 0, stream>>>(Wo, wob, 1048576);

  gemm_qkv<<<dim3(32, 24), 256, 0, stream>>>(xb, wqb, wkb, wvb, Qb, Kb, Vtb);
  attn_fwd<<<dim3(1024), 256, 0, stream>>>(Qb, Kb, Vtb, yb);
  gemm_out<<<dim3(32, 8), 256, 0, stream>>>(yb, wob, out);
}